// Round 2
// baseline (423.015 us; speedup 1.0000x reference)
//
#include <hip/hip_runtime.h>

#define NUM_E 1024
#define DIM 64
#define NROWS 65536                  // 64*32*32
#define OUT0_SIZE 4194304            // 64*64*32*32
#define OUT1_OFF OUT0_SIZE
#define LOSS_OFF (OUT0_SIZE + 65536) // 4259840
#define KSPLIT 4
#define KCHUNK (NUM_E / KSPLIT)

// ---- MFMA-path constants ----
// MARGIN covers 2*ERR where ERR = bf16-rounding error of the -2*z.e dot
// (<=5.5e-4 for |z|_1<=72) + dropped-En term (<=6.1e-5) + fp32 grid slop
// (~2e-5)  =>  2*ERR ~= 1.3e-3.  6e-3 gives 4.6x slack. Validated R1.
#define MARGIN 6.0e-3f
#define WS_EB_OFF 4096               // eB frag-packed -2*bf16(e): 128 KB
#define WS_FLAG_OFF (4096 + 131072)  // mfma-layout self-test flag
#define WS_NEED (WS_FLAG_OFF + 16)

typedef float f32x4_t __attribute__((ext_vector_type(4)));
typedef short s16x8  __attribute__((ext_vector_type(8)));

// ---------------- prep: En_k = np.sum(e_k*e_k) in numpy pairwise order ----
__device__ __forceinline__ float np_sumsq64_arr(const float* __restrict__ x) {
#pragma clang fp contract(off)
    float r[8];
#pragma unroll
    for (int j = 0; j < 8; ++j) r[j] = x[j] * x[j];
#pragma unroll
    for (int i = 8; i < 64; i += 8) {
#pragma unroll
        for (int j = 0; j < 8; ++j) {
            float p = x[i + j] * x[i + j];
            r[j] = r[j] + p;
        }
    }
    return ((r[0] + r[1]) + (r[2] + r[3])) + ((r[4] + r[5]) + (r[6] + r[7]));
}

// RNE float->bf16 (no NaN inputs here)
__device__ __forceinline__ unsigned short f2bf(float x) {
    unsigned u = __float_as_uint(x);
    u += 0x7FFFu + ((u >> 16) & 1u);
    return (unsigned short)(u >> 16);
}

__device__ __forceinline__ s16x8 pack_bf8(float4 a, float4 b) {
    s16x8 v;
    v[0] = (short)f2bf(a.x); v[1] = (short)f2bf(a.y);
    v[2] = (short)f2bf(a.z); v[3] = (short)f2bf(a.w);
    v[4] = (short)f2bf(b.x); v[5] = (short)f2bf(b.y);
    v[6] = (short)f2bf(b.z); v[7] = (short)f2bf(b.w);
    return v;
}

#define SQ8(A, B)                                              \
    { float p;                                                 \
      p = A.x*A.x; r0 = r0 + p;  p = A.y*A.y; r1 = r1 + p;     \
      p = A.z*A.z; r2 = r2 + p;  p = A.w*A.w; r3 = r3 + p;     \
      p = B.x*B.x; r4 = r4 + p;  p = B.y*B.y; r5 = r5 + p;     \
      p = B.z*B.z; r6 = r6 + p;  p = B.w*B.w; r7 = r7 + p; }

#define DOT4(Q, ZQ)                                            \
    { float4 ev = ep[Q];                                       \
      m = fmaf(ev.x, ZQ.x, m); m = fmaf(ev.y, ZQ.y, m);        \
      m = fmaf(ev.z, ZQ.z, m); m = fmaf(ev.w, ZQ.w, m); }

#define EPI4(Q, ZQ)                                            \
    { float4 evv = erp[Q]; float df;                           \
      o0[(size_t)(4*Q+0)*1024] = evv.x; df = evv.x - ZQ.x; lsum = fmaf(df,df,lsum); \
      o0[(size_t)(4*Q+1)*1024] = evv.y; df = evv.y - ZQ.y; lsum = fmaf(df,df,lsum); \
      o0[(size_t)(4*Q+2)*1024] = evv.z; df = evv.z - ZQ.z; lsum = fmaf(df,df,lsum); \
      o0[(size_t)(4*Q+3)*1024] = evv.w; df = evv.w - ZQ.w; lsum = fmaf(df,df,lsum); }

// ======================= OLD (fallback) kernels =======================
__global__ __launch_bounds__(256) void vq_prep_kernel(const float* __restrict__ e,
                                                      float* __restrict__ En,
                                                      float* __restrict__ out) {
    const int k = blockIdx.x * 256 + threadIdx.x;
    if (k == 0) out[LOSS_OFF] = 0.0f;
    float xr[DIM];
    const float4* ep = (const float4*)(e + (size_t)k * DIM);
#pragma unroll
    for (int i = 0; i < 16; ++i) {
        float4 v = ep[i];
        xr[4*i+0] = v.x; xr[4*i+1] = v.y; xr[4*i+2] = v.z; xr[4*i+3] = v.w;
    }
    En[k] = np_sumsq64_arr(xr);
}

__global__
__attribute__((amdgpu_flat_work_group_size(256, 256), amdgpu_waves_per_eu(4, 4)))
void vq_fused_kernel(const float* __restrict__ z,
                     const float* __restrict__ e,
                     const float* __restrict__ En,
                     float* __restrict__ out) {
    const int lane = threadIdx.x & 63;
    const int q = __builtin_amdgcn_readfirstlane((int)(threadIdx.x >> 6));
    const int n = blockIdx.x * 64 + lane;

    float4 z0,z1,z2,z3,z4,z5,z6,z7,z8,z9,z10,z11,z12,z13,z14,z15;
    {
        const float4* zp = (const float4*)(z + (size_t)n * DIM);
        z0=zp[0]; z1=zp[1]; z2=zp[2]; z3=zp[3]; z4=zp[4]; z5=zp[5]; z6=zp[6]; z7=zp[7];
        z8=zp[8]; z9=zp[9]; z10=zp[10]; z11=zp[11]; z12=zp[12]; z13=zp[13]; z14=zp[14]; z15=zp[15];
    }
    float A;
    {
#pragma clang fp contract(off)
        float r0,r1,r2,r3,r4,r5,r6,r7;
        { float p;
          p = z0.x*z0.x; r0 = p;  p = z0.y*z0.y; r1 = p;
          p = z0.z*z0.z; r2 = p;  p = z0.w*z0.w; r3 = p;
          p = z1.x*z1.x; r4 = p;  p = z1.y*z1.y; r5 = p;
          p = z1.z*z1.z; r6 = p;  p = z1.w*z1.w; r7 = p; }
        SQ8(z2,  z3)  SQ8(z4,  z5)  SQ8(z6,  z7)
        SQ8(z8,  z9)  SQ8(z10, z11) SQ8(z12, z13) SQ8(z14, z15)
        A = ((r0 + r1) + (r2 + r3)) + ((r4 + r5) + (r6 + r7));
    }

    const int k0 = q * KCHUNK;
    float best = 3.4e38f;
    int bk = k0;
#pragma unroll 1
    for (int kk = 0; kk < KCHUNK; ++kk) {
        const int k = k0 + kk;
        const float4* ep = (const float4*)(e + (size_t)k * DIM);
        float m = 0.0f;
        DOT4(0,  z0)  DOT4(1,  z1)  DOT4(2,  z2)  DOT4(3,  z3)
        DOT4(4,  z4)  DOT4(5,  z5)  DOT4(6,  z6)  DOT4(7,  z7)
        DOT4(8,  z8)  DOT4(9,  z9)  DOT4(10, z10) DOT4(11, z11)
        DOT4(12, z12) DOT4(13, z13) DOT4(14, z14) DOT4(15, z15)
        float s;
        {
#pragma clang fp contract(off)
            float twoM = 2.0f * m;
            float t = A - twoM;
            s = t + En[k];
        }
        if (s < best) { best = s; bk = k; }
    }

    __shared__ float ls[KSPLIT][64];
    __shared__ int   li[KSPLIT][64];
    ls[q][lane] = best;
    li[q][lane] = bk;
    __syncthreads();

    if (threadIdx.x < 64) {
        float b0 = ls[0][lane];
        int   kb = li[0][lane];
#pragma unroll
        for (int qq = 1; qq < KSPLIT; ++qq) {
            float sq = ls[qq][lane];
            if (sq < b0) { b0 = sq; kb = li[qq][lane]; }
        }
        const int b  = n >> 10;
        const int hw = n & 1023;
        const float4* erp = (const float4*)(e + (size_t)kb * DIM);
        float* o0 = out + (size_t)b * 65536 + hw;
        float lsum = 0.0f;
        EPI4(0,  z0)  EPI4(1,  z1)  EPI4(2,  z2)  EPI4(3,  z3)
        EPI4(4,  z4)  EPI4(5,  z5)  EPI4(6,  z6)  EPI4(7,  z7)
        EPI4(8,  z8)  EPI4(9,  z9)  EPI4(10, z10) EPI4(11, z11)
        EPI4(12, z12) EPI4(13, z13) EPI4(14, z14) EPI4(15, z15)
        out[OUT1_OFF + n] = (float)kb;
#pragma unroll
        for (int off = 32; off > 0; off >>= 1)
            lsum += __shfl_down(lsum, off, 64);
        if (lane == 0)
            atomicAdd(&out[LOSS_OFF], lsum * (1.25f / 4194304.0f));
    }
}

// ======================= MFMA path =======================
// exact fp32 rescore, bit-identical to the validated old-kernel inner loop
__device__ __forceinline__ float vq_rescore(const int k,
        const float* __restrict__ e, const float* __restrict__ En, const float A,
        const float4 z0, const float4 z1, const float4 z2, const float4 z3,
        const float4 z4, const float4 z5, const float4 z6, const float4 z7,
        const float4 z8, const float4 z9, const float4 z10, const float4 z11,
        const float4 z12, const float4 z13, const float4 z14, const float4 z15) {
    const float4* ep = (const float4*)(e + (size_t)k * DIM);
    float m = 0.0f;
    DOT4(0,  z0)  DOT4(1,  z1)  DOT4(2,  z2)  DOT4(3,  z3)
    DOT4(4,  z4)  DOT4(5,  z5)  DOT4(6,  z6)  DOT4(7,  z7)
    DOT4(8,  z8)  DOT4(9,  z9)  DOT4(10, z10) DOT4(11, z11)
    DOT4(12, z12) DOT4(13, z13) DOT4(14, z14) DOT4(15, z15)
    float s;
    {
#pragma clang fp contract(off)
        const float twoM = 2.0f * m;
        const float t = A - twoM;
        s = t + En[k];
    }
    return s;
}

// prep2: En (exact, unchanged math) + eB = -2*bf16(e) packed in B-frag order
//   eB layout: [group G=0..63][frag f=0..1][lane l=0..63][8 bf16]
//   lane l of (G,f) holds e[G*16 + (l&15)][f*32 + (l>>4)*8 + 0..7]
// + MFMA fragment-layout self-test (asymmetric); flag!=0 -> main kernel takes
//   the exact full-scan path for every row (slow but correct).
__global__ __launch_bounds__(256) void vq_prep2(const float* __restrict__ e,
                                                float* __restrict__ En,
                                                unsigned short* __restrict__ eB,
                                                int* __restrict__ flg,
                                                float* __restrict__ out) {
    const int tid = blockIdx.x * 256 + threadIdx.x;   // 0..8191
    if (tid == 0) out[LOSS_OFF] = 0.0f;
    {
        const int G = tid >> 7, rem = tid & 127, f = rem >> 6, l = rem & 63;
        const int code = G * 16 + (l & 15);
        const int d0 = f * 32 + ((l >> 4) << 3);
        const float4* sp = (const float4*)(e + (size_t)code * DIM + d0);
        float4 a = sp[0], b = sp[1];
        a.x *= -2.f; a.y *= -2.f; a.z *= -2.f; a.w *= -2.f;
        b.x *= -2.f; b.y *= -2.f; b.z *= -2.f; b.w *= -2.f;
        s16x8 v = pack_bf8(a, b);
        *(s16x8*)(eB + (size_t)tid * 8) = v;
    }
    if (tid < NUM_E) {
        float xr[DIM];
        const float4* ep = (const float4*)(e + (size_t)tid * DIM);
#pragma unroll
        for (int i = 0; i < 16; ++i) {
            float4 v = ep[i];
            xr[4*i+0] = v.x; xr[4*i+1] = v.y; xr[4*i+2] = v.z; xr[4*i+3] = v.w;
        }
        En[tid] = np_sumsq64_arr(xr);
    }
    // ---- MFMA layout self-test (block 0, wave 0) ----
    if (blockIdx.x == 0 && threadIdx.x < 64) {
        const int l = threadIdx.x, cc = l & 15, hh = l >> 4;
        s16x8 ta, tb;
#pragma unroll
        for (int j = 0; j < 8; ++j) {
            const int k = hh * 8 + j;
            ta[j] = (short)((cc == 0) ? f2bf((float)(k + 1)) : 0);
            tb[j] = (short)((cc == 0) ? f2bf((float)(2 * k + 1))
                          : (cc == 3 && k == 2) ? f2bf(1.0f) : 0);
        }
        f32x4_t td = {0.f, 0.f, 0.f, 0.f};
        td = __builtin_amdgcn_mfma_f32_16x16x32_bf16(ta, tb, td, 0, 0, 0);
        int ok = 1;
#pragma unroll
        for (int j = 0; j < 4; ++j) {
            const int row = hh * 4 + j;
            const float expv = (cc == 0) ? (row == 0 ? 22352.0f : 0.0f)
                             : (cc == 3) ? (row == 0 ? 3.0f : 0.0f) : 0.0f;
            ok = ok && (td[j] == expv);
        }
        const unsigned long long bal = __ballot(ok);
        if (l == 0) flg[0] = (bal == 0xFFFFFFFFFFFFFFFFULL) ? 0 : 1;
    }
}

// main: 128 thr = 2 waves x 32 rows; 64 rows/block; grid 1024.
// eB (128 KB) is L2-resident -> B fragments read STRAIGHT FROM GLOBAL,
// no LDS staging, no barriers in the scan (R1 was barrier/latency-bound:
// MfmaUtil 1.8%, 8 stage+sync rounds, En load on the MFMA critical path).
// En is DROPPED from the bf16 scores (|En|<=6.1e-5 << MARGIN budget);
// acc init = 0. phase1: per-row bf16 min. phase2: collect codes within
// MARGIN of min. epilogue: exact fp32 rescore (validated rounding grid).
__global__ __launch_bounds__(128)
void vq_mfma_kernel(const float* __restrict__ z,
                    const float* __restrict__ e,
                    const float* __restrict__ En,
                    const unsigned short* __restrict__ eB,
                    const int* __restrict__ flg,
                    float* __restrict__ out) {
    __shared__ int candcnt[64];
    __shared__ int candk[64][15];

    const int tid  = threadIdx.x;
    const int lane = tid & 63;
    const int w    = __builtin_amdgcn_readfirstlane(tid >> 6);
    const int cc   = lane & 15;   // B-col (code within group) / D-col
    const int hh   = lane >> 4;   // k-subgroup / D-row-group
    const int n0   = blockIdx.x * 64;
    const int bad  = flg[0];

    // each wave inits its own 32 rows (no barrier needed before own atomics)
    if (lane < 32) candcnt[w * 32 + lane] = 0;

    // z fragments (bf16): rows w*32+cc (set A) and +16 (set B), K halves 0/1
    s16x8 az0, az1, az2, az3;
    {
        const float* zr0 = z + (size_t)(n0 + w * 32 + cc) * DIM + hh * 8;
        const float* zr1 = zr0 + (size_t)16 * DIM;
        az0 = pack_bf8(*(const float4*)(zr0),      *(const float4*)(zr0 + 4));
        az1 = pack_bf8(*(const float4*)(zr0 + 32), *(const float4*)(zr0 + 36));
        az2 = pack_bf8(*(const float4*)(zr1),      *(const float4*)(zr1 + 4));
        az3 = pack_bf8(*(const float4*)(zr1 + 32), *(const float4*)(zr1 + 36));
    }

    if (!bad) {
        const s16x8* ebp = (const s16x8*)eB;   // [u*128 + f*64 + lane]

        // ---------------- phase 1: min scan (no barriers) ----------------
        float b1v[8];
#pragma unroll
        for (int j = 0; j < 8; ++j) b1v[j] = 3.4e38f;

#pragma unroll 8
        for (int u = 0; u < 64; ++u) {
            const s16x8 eb0 = ebp[u * 128 + lane];
            const s16x8 eb1 = ebp[u * 128 + 64 + lane];
            f32x4_t accA = {0.f, 0.f, 0.f, 0.f};
            f32x4_t accB = {0.f, 0.f, 0.f, 0.f};
            accA = __builtin_amdgcn_mfma_f32_16x16x32_bf16(az0, eb0, accA, 0, 0, 0);
            accA = __builtin_amdgcn_mfma_f32_16x16x32_bf16(az1, eb1, accA, 0, 0, 0);
            accB = __builtin_amdgcn_mfma_f32_16x16x32_bf16(az2, eb0, accB, 0, 0, 0);
            accB = __builtin_amdgcn_mfma_f32_16x16x32_bf16(az3, eb1, accB, 0, 0, 0);
#pragma unroll
            for (int j = 0; j < 4; ++j) {
                b1v[j]     = fminf(b1v[j],     accA[j]);
                b1v[j + 4] = fminf(b1v[j + 4], accB[j]);
            }
        }

        // per-row bf16 min across the 16 cc-classes -> threshold
        float th[8];
#pragma unroll
        for (int j = 0; j < 8; ++j) {
            float mv = b1v[j];
            mv = fminf(mv, __shfl_xor(mv, 1));
            mv = fminf(mv, __shfl_xor(mv, 2));
            mv = fminf(mv, __shfl_xor(mv, 4));
            mv = fminf(mv, __shfl_xor(mv, 8));
            th[j] = mv + MARGIN;
        }

        // ---------------- phase 2: candidate collection ----------------
#pragma unroll 4
        for (int u = 0; u < 64; ++u) {
            const s16x8 eb0 = ebp[u * 128 + lane];
            const s16x8 eb1 = ebp[u * 128 + 64 + lane];
            f32x4_t accA = {0.f, 0.f, 0.f, 0.f};
            f32x4_t accB = {0.f, 0.f, 0.f, 0.f};
            accA = __builtin_amdgcn_mfma_f32_16x16x32_bf16(az0, eb0, accA, 0, 0, 0);
            accA = __builtin_amdgcn_mfma_f32_16x16x32_bf16(az1, eb1, accA, 0, 0, 0);
            accB = __builtin_amdgcn_mfma_f32_16x16x32_bf16(az2, eb0, accB, 0, 0, 0);
            accB = __builtin_amdgcn_mfma_f32_16x16x32_bf16(az3, eb1, accB, 0, 0, 0);
            float worst = accA[0] - th[0];
            worst = fminf(worst, accA[1] - th[1]);
            worst = fminf(worst, accA[2] - th[2]);
            worst = fminf(worst, accA[3] - th[3]);
            worst = fminf(worst, accB[0] - th[4]);
            worst = fminf(worst, accB[1] - th[5]);
            worst = fminf(worst, accB[2] - th[6]);
            worst = fminf(worst, accB[3] - th[7]);
            if (__any(worst <= 0.0f)) {
                const int kc = u * 16 + cc;
#pragma unroll
                for (int j = 0; j < 4; ++j) {
                    if (accA[j] <= th[j]) {
                        const int rr = w * 32 + hh * 4 + j;
                        const int slot = atomicAdd(&candcnt[rr], 1);
                        if (slot < 15) candk[rr][slot] = kc;
                    }
                    if (accB[j] <= th[j + 4]) {
                        const int rr = w * 32 + 16 + hh * 4 + j;
                        const int slot = atomicAdd(&candcnt[rr], 1);
                        if (slot < 15) candk[rr][slot] = kc;
                    }
                }
            }
        }
    }
    __syncthreads();

    // ---------------- epilogue: exact rescore + outputs (wave 0) ----------
    if (tid < 64) {
        const int r = tid;
        const int n = n0 + r;
        float4 z0,z1,z2,z3,z4,z5,z6,z7,z8,z9,z10,z11,z12,z13,z14,z15;
        {
            const float4* zp = (const float4*)(z + (size_t)n * DIM);
            z0=zp[0]; z1=zp[1]; z2=zp[2]; z3=zp[3]; z4=zp[4]; z5=zp[5]; z6=zp[6]; z7=zp[7];
            z8=zp[8]; z9=zp[9]; z10=zp[10]; z11=zp[11]; z12=zp[12]; z13=zp[13]; z14=zp[14]; z15=zp[15];
        }
        float A;
        {
#pragma clang fp contract(off)
            float r0,r1,r2,r3,r4,r5,r6,r7;
            { float p;
              p = z0.x*z0.x; r0 = p;  p = z0.y*z0.y; r1 = p;
              p = z0.z*z0.z; r2 = p;  p = z0.w*z0.w; r3 = p;
              p = z1.x*z1.x; r4 = p;  p = z1.y*z1.y; r5 = p;
              p = z1.z*z1.z; r6 = p;  p = z1.w*z1.w; r7 = p; }
            SQ8(z2,  z3)  SQ8(z4,  z5)  SQ8(z6,  z7)
            SQ8(z8,  z9)  SQ8(z10, z11) SQ8(z12, z13) SQ8(z14, z15)
            A = ((r0 + r1) + (r2 + r3)) + ((r4 + r5) + (r6 + r7));
        }
#define RS(K) vq_rescore((K), e, En, A, z0,z1,z2,z3,z4,z5,z6,z7,z8,z9,z10,z11,z12,z13,z14,z15)
        const int cnt = bad ? 0 : candcnt[r];
        float best = 3.4e38f;
        int bk = 0x7FFFFFFF;
        if (cnt >= 1 && cnt <= 15) {
            for (int i = 0; i < cnt; ++i) {
                const int k = candk[r][i];
                const float s = RS(k);
                if (s < best || (s == best && k < bk)) { best = s; bk = k; }
            }
        }
        if ((unsigned)bk > 1023u) {   // bad-layout flag / overflow / none: exact full scan
            best = 3.4e38f; bk = 0;
            for (int k = 0; k < NUM_E; ++k) {
                const float s = RS(k);
                if (s < best) { best = s; bk = k; }
            }
        }
#undef RS
        const int b  = n >> 10;
        const int hw = n & 1023;
        const float4* erp = (const float4*)(e + (size_t)bk * DIM);
        float* o0 = out + (size_t)b * 65536 + hw;
        float lsum = 0.0f;
        EPI4(0,  z0)  EPI4(1,  z1)  EPI4(2,  z2)  EPI4(3,  z3)
        EPI4(4,  z4)  EPI4(5,  z5)  EPI4(6,  z6)  EPI4(7,  z7)
        EPI4(8,  z8)  EPI4(9,  z9)  EPI4(10, z10) EPI4(11, z11)
        EPI4(12, z12) EPI4(13, z13) EPI4(14, z14) EPI4(15, z15)
        out[OUT1_OFF + n] = (float)bk;
#pragma unroll
        for (int off = 32; off > 0; off >>= 1)
            lsum += __shfl_down(lsum, off, 64);
        if (tid == 0)
            atomicAdd(&out[LOSS_OFF], lsum * (1.25f / 4194304.0f));
    }
}

extern "C" void kernel_launch(void* const* d_in, const int* in_sizes, int n_in,
                              void* d_out, int out_size, void* d_ws, size_t ws_size,
                              hipStream_t stream) {
    const float* z = (const float*)d_in[0];       // [65536, 64] fp32
    const float* e = (const float*)d_in[1];       // [1024, 64] fp32
    float* out = (float*)d_out;
    float* En  = (float*)d_ws;                    // 1024 fp32 norms (4 KB)

    if (ws_size >= WS_NEED) {
        unsigned short* eB = (unsigned short*)((char*)d_ws + WS_EB_OFF);
        int* flg = (int*)((char*)d_ws + WS_FLAG_OFF);
        vq_prep2<<<32, 256, 0, stream>>>(e, En, eB, flg, out);
        vq_mfma_kernel<<<NROWS / 64, 128, 0, stream>>>(z, e, En, eB, flg, out);
    } else {
        vq_prep_kernel<<<NUM_E / 256, 256, 0, stream>>>(e, En, out);
        vq_fused_kernel<<<NROWS / 64, 256, 0, stream>>>(z, e, En, out);
    }
}

// Round 3
// 143.617 us; speedup vs baseline: 2.9454x; 2.9454x over previous
//
#include <hip/hip_runtime.h>

#define NUM_E 1024
#define DIM 64
#define NROWS 65536                  // 64*32*32
#define OUT0_SIZE 4194304            // 64*64*32*32
#define OUT1_OFF OUT0_SIZE
#define LOSS_OFF (OUT0_SIZE + 65536) // 4259840
#define KSPLIT 4
#define KCHUNK (NUM_E / KSPLIT)

// ---- MFMA-path constants ----
// Error bound for the bf16 score vs the exact fp32 grid:
//   2*ERR, ERR = bf16-input rounding (2*2^-8 * |z|_1 * max|e| <= 5.6e-4 at
//   |z|_1<=75) + dropped-En (<=6.1e-5) + fp32 accum slop (~1e-5) => ~1.3e-3.
// MARGIN = 2.5e-3 is 2.0x that bound. Score spread sigma ~ 9e-3, so the
// window is ~0.28 sigma -> expected candidates/row ~2 (R2's 6e-3 gave ~6
// and overflowed the 15-slot cap on a few rows -> 300us serial full scans).
#define MARGIN 2.5e-3f
#define CAND_CAP 31
#define WS_EB_OFF 4096               // eB frag-packed -2*bf16(e): 128 KB
#define WS_FLAG_OFF (4096 + 131072)  // mfma-layout self-test flag
#define WS_NEED (WS_FLAG_OFF + 16)

typedef float f32x4_t __attribute__((ext_vector_type(4)));
typedef short s16x8  __attribute__((ext_vector_type(8)));

// ---------------- prep: En_k = np.sum(e_k*e_k) in numpy pairwise order ----
__device__ __forceinline__ float np_sumsq64_arr(const float* __restrict__ x) {
#pragma clang fp contract(off)
    float r[8];
#pragma unroll
    for (int j = 0; j < 8; ++j) r[j] = x[j] * x[j];
#pragma unroll
    for (int i = 8; i < 64; i += 8) {
#pragma unroll
        for (int j = 0; j < 8; ++j) {
            float p = x[i + j] * x[i + j];
            r[j] = r[j] + p;
        }
    }
    return ((r[0] + r[1]) + (r[2] + r[3])) + ((r[4] + r[5]) + (r[6] + r[7]));
}

// RNE float->bf16 (no NaN inputs here)
__device__ __forceinline__ unsigned short f2bf(float x) {
    unsigned u = __float_as_uint(x);
    u += 0x7FFFu + ((u >> 16) & 1u);
    return (unsigned short)(u >> 16);
}

__device__ __forceinline__ s16x8 pack_bf8(float4 a, float4 b) {
    s16x8 v;
    v[0] = (short)f2bf(a.x); v[1] = (short)f2bf(a.y);
    v[2] = (short)f2bf(a.z); v[3] = (short)f2bf(a.w);
    v[4] = (short)f2bf(b.x); v[5] = (short)f2bf(b.y);
    v[6] = (short)f2bf(b.z); v[7] = (short)f2bf(b.w);
    return v;
}

#define SQ8(A, B)                                              \
    { float p;                                                 \
      p = A.x*A.x; r0 = r0 + p;  p = A.y*A.y; r1 = r1 + p;     \
      p = A.z*A.z; r2 = r2 + p;  p = A.w*A.w; r3 = r3 + p;     \
      p = B.x*B.x; r4 = r4 + p;  p = B.y*B.y; r5 = r5 + p;     \
      p = B.z*B.z; r6 = r6 + p;  p = B.w*B.w; r7 = r7 + p; }

#define DOT4(Q, ZQ)                                            \
    { float4 ev = ep[Q];                                       \
      m = fmaf(ev.x, ZQ.x, m); m = fmaf(ev.y, ZQ.y, m);        \
      m = fmaf(ev.z, ZQ.z, m); m = fmaf(ev.w, ZQ.w, m); }

#define EPI4(Q, ZQ)                                            \
    { float4 evv = erp[Q]; float df;                           \
      o0[(size_t)(4*Q+0)*1024] = evv.x; df = evv.x - ZQ.x; lsum = fmaf(df,df,lsum); \
      o0[(size_t)(4*Q+1)*1024] = evv.y; df = evv.y - ZQ.y; lsum = fmaf(df,df,lsum); \
      o0[(size_t)(4*Q+2)*1024] = evv.z; df = evv.z - ZQ.z; lsum = fmaf(df,df,lsum); \
      o0[(size_t)(4*Q+3)*1024] = evv.w; df = evv.w - ZQ.w; lsum = fmaf(df,df,lsum); }

// ======================= OLD (fallback) kernels =======================
__global__ __launch_bounds__(256) void vq_prep_kernel(const float* __restrict__ e,
                                                      float* __restrict__ En,
                                                      float* __restrict__ out) {
    const int k = blockIdx.x * 256 + threadIdx.x;
    if (k == 0) out[LOSS_OFF] = 0.0f;
    float xr[DIM];
    const float4* ep = (const float4*)(e + (size_t)k * DIM);
#pragma unroll
    for (int i = 0; i < 16; ++i) {
        float4 v = ep[i];
        xr[4*i+0] = v.x; xr[4*i+1] = v.y; xr[4*i+2] = v.z; xr[4*i+3] = v.w;
    }
    En[k] = np_sumsq64_arr(xr);
}

__global__
__attribute__((amdgpu_flat_work_group_size(256, 256), amdgpu_waves_per_eu(4, 4)))
void vq_fused_kernel(const float* __restrict__ z,
                     const float* __restrict__ e,
                     const float* __restrict__ En,
                     float* __restrict__ out) {
    const int lane = threadIdx.x & 63;
    const int q = __builtin_amdgcn_readfirstlane((int)(threadIdx.x >> 6));
    const int n = blockIdx.x * 64 + lane;

    float4 z0,z1,z2,z3,z4,z5,z6,z7,z8,z9,z10,z11,z12,z13,z14,z15;
    {
        const float4* zp = (const float4*)(z + (size_t)n * DIM);
        z0=zp[0]; z1=zp[1]; z2=zp[2]; z3=zp[3]; z4=zp[4]; z5=zp[5]; z6=zp[6]; z7=zp[7];
        z8=zp[8]; z9=zp[9]; z10=zp[10]; z11=zp[11]; z12=zp[12]; z13=zp[13]; z14=zp[14]; z15=zp[15];
    }
    float A;
    {
#pragma clang fp contract(off)
        float r0,r1,r2,r3,r4,r5,r6,r7;
        { float p;
          p = z0.x*z0.x; r0 = p;  p = z0.y*z0.y; r1 = p;
          p = z0.z*z0.z; r2 = p;  p = z0.w*z0.w; r3 = p;
          p = z1.x*z1.x; r4 = p;  p = z1.y*z1.y; r5 = p;
          p = z1.z*z1.z; r6 = p;  p = z1.w*z1.w; r7 = p; }
        SQ8(z2,  z3)  SQ8(z4,  z5)  SQ8(z6,  z7)
        SQ8(z8,  z9)  SQ8(z10, z11) SQ8(z12, z13) SQ8(z14, z15)
        A = ((r0 + r1) + (r2 + r3)) + ((r4 + r5) + (r6 + r7));
    }

    const int k0 = q * KCHUNK;
    float best = 3.4e38f;
    int bk = k0;
#pragma unroll 1
    for (int kk = 0; kk < KCHUNK; ++kk) {
        const int k = k0 + kk;
        const float4* ep = (const float4*)(e + (size_t)k * DIM);
        float m = 0.0f;
        DOT4(0,  z0)  DOT4(1,  z1)  DOT4(2,  z2)  DOT4(3,  z3)
        DOT4(4,  z4)  DOT4(5,  z5)  DOT4(6,  z6)  DOT4(7,  z7)
        DOT4(8,  z8)  DOT4(9,  z9)  DOT4(10, z10) DOT4(11, z11)
        DOT4(12, z12) DOT4(13, z13) DOT4(14, z14) DOT4(15, z15)
        float s;
        {
#pragma clang fp contract(off)
            float twoM = 2.0f * m;
            float t = A - twoM;
            s = t + En[k];
        }
        if (s < best) { best = s; bk = k; }
    }

    __shared__ float ls[KSPLIT][64];
    __shared__ int   li[KSPLIT][64];
    ls[q][lane] = best;
    li[q][lane] = bk;
    __syncthreads();

    if (threadIdx.x < 64) {
        float b0 = ls[0][lane];
        int   kb = li[0][lane];
#pragma unroll
        for (int qq = 1; qq < KSPLIT; ++qq) {
            float sq = ls[qq][lane];
            if (sq < b0) { b0 = sq; kb = li[qq][lane]; }
        }
        const int b  = n >> 10;
        const int hw = n & 1023;
        const float4* erp = (const float4*)(e + (size_t)kb * DIM);
        float* o0 = out + (size_t)b * 65536 + hw;
        float lsum = 0.0f;
        EPI4(0,  z0)  EPI4(1,  z1)  EPI4(2,  z2)  EPI4(3,  z3)
        EPI4(4,  z4)  EPI4(5,  z5)  EPI4(6,  z6)  EPI4(7,  z7)
        EPI4(8,  z8)  EPI4(9,  z9)  EPI4(10, z10) EPI4(11, z11)
        EPI4(12, z12) EPI4(13, z13) EPI4(14, z14) EPI4(15, z15)
        out[OUT1_OFF + n] = (float)kb;
#pragma unroll
        for (int off = 32; off > 0; off >>= 1)
            lsum += __shfl_down(lsum, off, 64);
        if (lane == 0)
            atomicAdd(&out[LOSS_OFF], lsum * (1.25f / 4194304.0f));
    }
}

// ======================= MFMA path =======================
// exact fp32 rescore, bit-identical to the validated old-kernel inner loop
__device__ __forceinline__ float vq_rescore(const int k,
        const float* __restrict__ e, const float* __restrict__ En, const float A,
        const float4 z0, const float4 z1, const float4 z2, const float4 z3,
        const float4 z4, const float4 z5, const float4 z6, const float4 z7,
        const float4 z8, const float4 z9, const float4 z10, const float4 z11,
        const float4 z12, const float4 z13, const float4 z14, const float4 z15) {
    const float4* ep = (const float4*)(e + (size_t)k * DIM);
    float m = 0.0f;
    DOT4(0,  z0)  DOT4(1,  z1)  DOT4(2,  z2)  DOT4(3,  z3)
    DOT4(4,  z4)  DOT4(5,  z5)  DOT4(6,  z6)  DOT4(7,  z7)
    DOT4(8,  z8)  DOT4(9,  z9)  DOT4(10, z10) DOT4(11, z11)
    DOT4(12, z12) DOT4(13, z13) DOT4(14, z14) DOT4(15, z15)
    float s;
    {
#pragma clang fp contract(off)
        const float twoM = 2.0f * m;
        const float t = A - twoM;
        s = t + En[k];
    }
    return s;
}

// prep2: En (exact, unchanged math) + eB = -2*bf16(e) packed in B-frag order
//   eB layout: [group G=0..63][frag f=0..1][lane l=0..63][8 bf16]
//   lane l of (G,f) holds e[G*16 + (l&15)][f*32 + (l>>4)*8 + 0..7]
// + MFMA fragment-layout self-test (asymmetric); flag!=0 -> main kernel takes
//   the exact full-scan path for every row (slow but correct).
__global__ __launch_bounds__(256) void vq_prep2(const float* __restrict__ e,
                                                float* __restrict__ En,
                                                unsigned short* __restrict__ eB,
                                                int* __restrict__ flg,
                                                float* __restrict__ out) {
    const int tid = blockIdx.x * 256 + threadIdx.x;   // 0..8191
    if (tid == 0) out[LOSS_OFF] = 0.0f;
    {
        const int G = tid >> 7, rem = tid & 127, f = rem >> 6, l = rem & 63;
        const int code = G * 16 + (l & 15);
        const int d0 = f * 32 + ((l >> 4) << 3);
        const float4* sp = (const float4*)(e + (size_t)code * DIM + d0);
        float4 a = sp[0], b = sp[1];
        a.x *= -2.f; a.y *= -2.f; a.z *= -2.f; a.w *= -2.f;
        b.x *= -2.f; b.y *= -2.f; b.z *= -2.f; b.w *= -2.f;
        s16x8 v = pack_bf8(a, b);
        *(s16x8*)(eB + (size_t)tid * 8) = v;
    }
    if (tid < NUM_E) {
        float xr[DIM];
        const float4* ep = (const float4*)(e + (size_t)tid * DIM);
#pragma unroll
        for (int i = 0; i < 16; ++i) {
            float4 v = ep[i];
            xr[4*i+0] = v.x; xr[4*i+1] = v.y; xr[4*i+2] = v.z; xr[4*i+3] = v.w;
        }
        En[tid] = np_sumsq64_arr(xr);
    }
    // ---- MFMA layout self-test (block 0, wave 0) ----
    if (blockIdx.x == 0 && threadIdx.x < 64) {
        const int l = threadIdx.x, cc = l & 15, hh = l >> 4;
        s16x8 ta, tb;
#pragma unroll
        for (int j = 0; j < 8; ++j) {
            const int k = hh * 8 + j;
            ta[j] = (short)((cc == 0) ? f2bf((float)(k + 1)) : 0);
            tb[j] = (short)((cc == 0) ? f2bf((float)(2 * k + 1))
                          : (cc == 3 && k == 2) ? f2bf(1.0f) : 0);
        }
        f32x4_t td = {0.f, 0.f, 0.f, 0.f};
        td = __builtin_amdgcn_mfma_f32_16x16x32_bf16(ta, tb, td, 0, 0, 0);
        int ok = 1;
#pragma unroll
        for (int j = 0; j < 4; ++j) {
            const int row = hh * 4 + j;
            const float expv = (cc == 0) ? (row == 0 ? 22352.0f : 0.0f)
                             : (cc == 3) ? (row == 0 ? 3.0f : 0.0f) : 0.0f;
            ok = ok && (td[j] == expv);
        }
        const unsigned long long bal = __ballot(ok);
        if (l == 0) flg[0] = (bal == 0xFFFFFFFFFFFFFFFFULL) ? 0 : 1;
    }
}

// main: 128 thr = 2 waves x 32 rows; 64 rows/block; grid 1024.
// R2 post-mortem: time was dominated by (a) z0..z15 spilled to scratch
// (VGPR_Count 68 — allocator targeted 7 waves/EU) and (b) a few rows
// overflowing the 15-slot candidate cap (MARGIN 6e-3 ~ 0.66 sigma of the
// score spread -> ~6 cands/row) -> lane-serial 1024-code full scans on
// spilled z ~ 300+us each, setting the wall time. Fixes: launch_bounds
// (128,2) => 256-VGPR budget (no spill); MARGIN 2.5e-3 (2.0x the analytic
// error bound); cap 31; wave-split epilogue (no barriers at all).
__global__ __launch_bounds__(128, 2)
void vq_mfma_kernel(const float* __restrict__ z,
                    const float* __restrict__ e,
                    const float* __restrict__ En,
                    const unsigned short* __restrict__ eB,
                    const int* __restrict__ flg,
                    float* __restrict__ out) {
    __shared__ int candcnt[64];
    __shared__ int candk[64][CAND_CAP];

    const int tid  = threadIdx.x;
    const int lane = tid & 63;
    const int w    = __builtin_amdgcn_readfirstlane(tid >> 6);
    const int cc   = lane & 15;   // B-col (code within group) / A-row
    const int hh   = lane >> 4;   // k-subgroup / D-row-group
    const int n0   = blockIdx.x * 64;
    const int bad  = flg[0];

    // each wave owns rows [w*32, w*32+32): init, scan, collect, rescore —
    // no inter-wave communication, zero barriers.
    if (lane < 32) candcnt[w * 32 + lane] = 0;

    // z fragments (bf16): rows w*32+cc (set A) and +16 (set B), K halves 0/1
    s16x8 az0, az1, az2, az3;
    {
        const float* zr0 = z + (size_t)(n0 + w * 32 + cc) * DIM + hh * 8;
        const float* zr1 = zr0 + (size_t)16 * DIM;
        az0 = pack_bf8(*(const float4*)(zr0),      *(const float4*)(zr0 + 4));
        az1 = pack_bf8(*(const float4*)(zr0 + 32), *(const float4*)(zr0 + 36));
        az2 = pack_bf8(*(const float4*)(zr1),      *(const float4*)(zr1 + 4));
        az3 = pack_bf8(*(const float4*)(zr1 + 32), *(const float4*)(zr1 + 36));
    }

    if (!bad) {
        const s16x8* ebp = (const s16x8*)eB;   // [u*128 + f*64 + lane]

        // ---------------- phase 1: min scan (no barriers) ----------------
        float b1v[8];
#pragma unroll
        for (int j = 0; j < 8; ++j) b1v[j] = 3.4e38f;

#pragma unroll 8
        for (int u = 0; u < 64; ++u) {
            const s16x8 eb0 = ebp[u * 128 + lane];
            const s16x8 eb1 = ebp[u * 128 + 64 + lane];
            f32x4_t accA = {0.f, 0.f, 0.f, 0.f};
            f32x4_t accB = {0.f, 0.f, 0.f, 0.f};
            accA = __builtin_amdgcn_mfma_f32_16x16x32_bf16(az0, eb0, accA, 0, 0, 0);
            accA = __builtin_amdgcn_mfma_f32_16x16x32_bf16(az1, eb1, accA, 0, 0, 0);
            accB = __builtin_amdgcn_mfma_f32_16x16x32_bf16(az2, eb0, accB, 0, 0, 0);
            accB = __builtin_amdgcn_mfma_f32_16x16x32_bf16(az3, eb1, accB, 0, 0, 0);
#pragma unroll
            for (int j = 0; j < 4; ++j) {
                b1v[j]     = fminf(b1v[j],     accA[j]);
                b1v[j + 4] = fminf(b1v[j + 4], accB[j]);
            }
        }

        // per-row bf16 min across the 16 cc-classes -> threshold
        float th[8];
#pragma unroll
        for (int j = 0; j < 8; ++j) {
            float mv = b1v[j];
            mv = fminf(mv, __shfl_xor(mv, 1));
            mv = fminf(mv, __shfl_xor(mv, 2));
            mv = fminf(mv, __shfl_xor(mv, 4));
            mv = fminf(mv, __shfl_xor(mv, 8));
            th[j] = mv + MARGIN;
        }

        // ---------------- phase 2: candidate collection ----------------
#pragma unroll 4
        for (int u = 0; u < 64; ++u) {
            const s16x8 eb0 = ebp[u * 128 + lane];
            const s16x8 eb1 = ebp[u * 128 + 64 + lane];
            f32x4_t accA = {0.f, 0.f, 0.f, 0.f};
            f32x4_t accB = {0.f, 0.f, 0.f, 0.f};
            accA = __builtin_amdgcn_mfma_f32_16x16x32_bf16(az0, eb0, accA, 0, 0, 0);
            accA = __builtin_amdgcn_mfma_f32_16x16x32_bf16(az1, eb1, accA, 0, 0, 0);
            accB = __builtin_amdgcn_mfma_f32_16x16x32_bf16(az2, eb0, accB, 0, 0, 0);
            accB = __builtin_amdgcn_mfma_f32_16x16x32_bf16(az3, eb1, accB, 0, 0, 0);
            float worst = accA[0] - th[0];
            worst = fminf(worst, accA[1] - th[1]);
            worst = fminf(worst, accA[2] - th[2]);
            worst = fminf(worst, accA[3] - th[3]);
            worst = fminf(worst, accB[0] - th[4]);
            worst = fminf(worst, accB[1] - th[5]);
            worst = fminf(worst, accB[2] - th[6]);
            worst = fminf(worst, accB[3] - th[7]);
            if (__any(worst <= 0.0f)) {
                const int kc = u * 16 + cc;
#pragma unroll
                for (int j = 0; j < 4; ++j) {
                    if (accA[j] <= th[j]) {
                        const int rr = w * 32 + hh * 4 + j;
                        const int slot = atomicAdd(&candcnt[rr], 1);
                        if (slot < CAND_CAP) candk[rr][slot] = kc;
                    }
                    if (accB[j] <= th[j + 4]) {
                        const int rr = w * 32 + 16 + hh * 4 + j;
                        const int slot = atomicAdd(&candcnt[rr], 1);
                        if (slot < CAND_CAP) candk[rr][slot] = kc;
                    }
                }
            }
        }
    }

    // -------- epilogue: exact rescore + outputs (wave w, its 32 rows) -----
    if (lane < 32) {
        const int r = w * 32 + lane;
        const int n = n0 + r;
        float4 z0,z1,z2,z3,z4,z5,z6,z7,z8,z9,z10,z11,z12,z13,z14,z15;
        {
            const float4* zp = (const float4*)(z + (size_t)n * DIM);
            z0=zp[0]; z1=zp[1]; z2=zp[2]; z3=zp[3]; z4=zp[4]; z5=zp[5]; z6=zp[6]; z7=zp[7];
            z8=zp[8]; z9=zp[9]; z10=zp[10]; z11=zp[11]; z12=zp[12]; z13=zp[13]; z14=zp[14]; z15=zp[15];
        }
        float A;
        {
#pragma clang fp contract(off)
            float r0,r1,r2,r3,r4,r5,r6,r7;
            { float p;
              p = z0.x*z0.x; r0 = p;  p = z0.y*z0.y; r1 = p;
              p = z0.z*z0.z; r2 = p;  p = z0.w*z0.w; r3 = p;
              p = z1.x*z1.x; r4 = p;  p = z1.y*z1.y; r5 = p;
              p = z1.z*z1.z; r6 = p;  p = z1.w*z1.w; r7 = p; }
            SQ8(z2,  z3)  SQ8(z4,  z5)  SQ8(z6,  z7)
            SQ8(z8,  z9)  SQ8(z10, z11) SQ8(z12, z13) SQ8(z14, z15)
            A = ((r0 + r1) + (r2 + r3)) + ((r4 + r5) + (r6 + r7));
        }
#define RS(K) vq_rescore((K), e, En, A, z0,z1,z2,z3,z4,z5,z6,z7,z8,z9,z10,z11,z12,z13,z14,z15)
        const int cnt = bad ? 0 : candcnt[r];
        float best = 3.4e38f;
        int bk = 0x7FFFFFFF;
        if (cnt >= 1 && cnt <= CAND_CAP) {
            for (int i = 0; i < cnt; ++i) {
                const int k = candk[r][i];
                const float s = RS(k);
                if (s < best || (s == best && k < bk)) { best = s; bk = k; }
            }
        }
        if ((unsigned)bk > 1023u) {   // bad-layout flag / overflow: exact full scan
            best = 3.4e38f; bk = 0;
            for (int k = 0; k < NUM_E; ++k) {
                const float s = RS(k);
                if (s < best) { best = s; bk = k; }
            }
        }
#undef RS
        const int b  = n >> 10;
        const int hw = n & 1023;
        const float4* erp = (const float4*)(e + (size_t)bk * DIM);
        float* o0 = out + (size_t)b * 65536 + hw;
        float lsum = 0.0f;
        EPI4(0,  z0)  EPI4(1,  z1)  EPI4(2,  z2)  EPI4(3,  z3)
        EPI4(4,  z4)  EPI4(5,  z5)  EPI4(6,  z6)  EPI4(7,  z7)
        EPI4(8,  z8)  EPI4(9,  z9)  EPI4(10, z10) EPI4(11, z11)
        EPI4(12, z12) EPI4(13, z13) EPI4(14, z14) EPI4(15, z15)
        out[OUT1_OFF + n] = (float)bk;
#pragma unroll
        for (int off = 16; off > 0; off >>= 1)
            lsum += __shfl_down(lsum, off, 32);
        if (lane == 0)
            atomicAdd(&out[LOSS_OFF], lsum * (1.25f / 4194304.0f));
    }
}

extern "C" void kernel_launch(void* const* d_in, const int* in_sizes, int n_in,
                              void* d_out, int out_size, void* d_ws, size_t ws_size,
                              hipStream_t stream) {
    const float* z = (const float*)d_in[0];       // [65536, 64] fp32
    const float* e = (const float*)d_in[1];       // [1024, 64] fp32
    float* out = (float*)d_out;
    float* En  = (float*)d_ws;                    // 1024 fp32 norms (4 KB)

    if (ws_size >= WS_NEED) {
        unsigned short* eB = (unsigned short*)((char*)d_ws + WS_EB_OFF);
        int* flg = (int*)((char*)d_ws + WS_FLAG_OFF);
        vq_prep2<<<32, 256, 0, stream>>>(e, En, eB, flg, out);
        vq_mfma_kernel<<<NROWS / 64, 128, 0, stream>>>(z, e, En, eB, flg, out);
    } else {
        vq_prep_kernel<<<NUM_E / 256, 256, 0, stream>>>(e, En, out);
        vq_fused_kernel<<<NROWS / 64, 256, 0, stream>>>(z, e, En, out);
    }
}

// Round 4
// 133.113 us; speedup vs baseline: 3.1779x; 1.0789x over previous
//
#include <hip/hip_runtime.h>

#define NUM_E 1024
#define DIM 64
#define NROWS 65536                  // 64*32*32
#define OUT0_SIZE 4194304            // 64*64*32*32
#define OUT1_OFF OUT0_SIZE
#define LOSS_OFF (OUT0_SIZE + 65536) // 4259840
#define KSPLIT 4
#define KCHUNK (NUM_E / KSPLIT)

// ---- MFMA-path constants ----
// Error bound for the bf16 score vs the exact fp32 grid:
//   2*ERR, ERR = bf16-input rounding (2*2^-8 * |z|_1 * max|e| <= 5.6e-4 at
//   |z|_1<=75) + dropped-En (<=6.1e-5) + fp32 accum slop (~1e-5) => ~1.3e-3.
// MARGIN = 2.5e-3 is 2.0x that bound (validated R3: passed, absmax equal to
// the exact kernel's). Expected candidates/row ~1.7; CAP 23 => P(overflow)
// ~1e-15/row; overflow falls back to the exact full scan (correctness net).
#define MARGIN 2.5e-3f
#define CAND_CAP 23
#define WS_EB_OFF 4096               // eB frag-packed -2*bf16(e): 128 KB
#define WS_FLAG_OFF (4096 + 131072)  // mfma-layout self-test flag
#define WS_NEED (WS_FLAG_OFF + 16)

typedef float f32x4_t __attribute__((ext_vector_type(4)));
typedef short s16x8  __attribute__((ext_vector_type(8)));

#define AS1C(p) ((const __attribute__((address_space(1))) void*)(p))
#define AS3P(p) ((__attribute__((address_space(3))) void*)(p))

// ---------------- prep: En_k = np.sum(e_k*e_k) in numpy pairwise order ----
__device__ __forceinline__ float np_sumsq64_arr(const float* __restrict__ x) {
#pragma clang fp contract(off)
    float r[8];
#pragma unroll
    for (int j = 0; j < 8; ++j) r[j] = x[j] * x[j];
#pragma unroll
    for (int i = 8; i < 64; i += 8) {
#pragma unroll
        for (int j = 0; j < 8; ++j) {
            float p = x[i + j] * x[i + j];
            r[j] = r[j] + p;
        }
    }
    return ((r[0] + r[1]) + (r[2] + r[3])) + ((r[4] + r[5]) + (r[6] + r[7]));
}

// RNE float->bf16 (no NaN inputs here)
__device__ __forceinline__ unsigned short f2bf(float x) {
    unsigned u = __float_as_uint(x);
    u += 0x7FFFu + ((u >> 16) & 1u);
    return (unsigned short)(u >> 16);
}

__device__ __forceinline__ s16x8 pack_bf8(float4 a, float4 b) {
    s16x8 v;
    v[0] = (short)f2bf(a.x); v[1] = (short)f2bf(a.y);
    v[2] = (short)f2bf(a.z); v[3] = (short)f2bf(a.w);
    v[4] = (short)f2bf(b.x); v[5] = (short)f2bf(b.y);
    v[6] = (short)f2bf(b.z); v[7] = (short)f2bf(b.w);
    return v;
}

#define SQ8(A, B)                                              \
    { float p;                                                 \
      p = A.x*A.x; r0 = r0 + p;  p = A.y*A.y; r1 = r1 + p;     \
      p = A.z*A.z; r2 = r2 + p;  p = A.w*A.w; r3 = r3 + p;     \
      p = B.x*B.x; r4 = r4 + p;  p = B.y*B.y; r5 = r5 + p;     \
      p = B.z*B.z; r6 = r6 + p;  p = B.w*B.w; r7 = r7 + p; }

#define DOT4(Q, ZQ)                                            \
    { float4 ev = ep[Q];                                       \
      m = fmaf(ev.x, ZQ.x, m); m = fmaf(ev.y, ZQ.y, m);        \
      m = fmaf(ev.z, ZQ.z, m); m = fmaf(ev.w, ZQ.w, m); }

#define EPI4(Q, ZQ)                                            \
    { float4 evv = erp[Q]; float df;                           \
      o0[(size_t)(4*Q+0)*1024] = evv.x; df = evv.x - ZQ.x; lsum = fmaf(df,df,lsum); \
      o0[(size_t)(4*Q+1)*1024] = evv.y; df = evv.y - ZQ.y; lsum = fmaf(df,df,lsum); \
      o0[(size_t)(4*Q+2)*1024] = evv.z; df = evv.z - ZQ.z; lsum = fmaf(df,df,lsum); \
      o0[(size_t)(4*Q+3)*1024] = evv.w; df = evv.w - ZQ.w; lsum = fmaf(df,df,lsum); }

// ======================= OLD (fallback) kernels =======================
__global__ __launch_bounds__(256) void vq_prep_kernel(const float* __restrict__ e,
                                                      float* __restrict__ En,
                                                      float* __restrict__ out) {
    const int k = blockIdx.x * 256 + threadIdx.x;
    if (k == 0) out[LOSS_OFF] = 0.0f;
    float xr[DIM];
    const float4* ep = (const float4*)(e + (size_t)k * DIM);
#pragma unroll
    for (int i = 0; i < 16; ++i) {
        float4 v = ep[i];
        xr[4*i+0] = v.x; xr[4*i+1] = v.y; xr[4*i+2] = v.z; xr[4*i+3] = v.w;
    }
    En[k] = np_sumsq64_arr(xr);
}

__global__
__attribute__((amdgpu_flat_work_group_size(256, 256), amdgpu_waves_per_eu(4, 4)))
void vq_fused_kernel(const float* __restrict__ z,
                     const float* __restrict__ e,
                     const float* __restrict__ En,
                     float* __restrict__ out) {
    const int lane = threadIdx.x & 63;
    const int q = __builtin_amdgcn_readfirstlane((int)(threadIdx.x >> 6));
    const int n = blockIdx.x * 64 + lane;

    float4 z0,z1,z2,z3,z4,z5,z6,z7,z8,z9,z10,z11,z12,z13,z14,z15;
    {
        const float4* zp = (const float4*)(z + (size_t)n * DIM);
        z0=zp[0]; z1=zp[1]; z2=zp[2]; z3=zp[3]; z4=zp[4]; z5=zp[5]; z6=zp[6]; z7=zp[7];
        z8=zp[8]; z9=zp[9]; z10=zp[10]; z11=zp[11]; z12=zp[12]; z13=zp[13]; z14=zp[14]; z15=zp[15];
    }
    float A;
    {
#pragma clang fp contract(off)
        float r0,r1,r2,r3,r4,r5,r6,r7;
        { float p;
          p = z0.x*z0.x; r0 = p;  p = z0.y*z0.y; r1 = p;
          p = z0.z*z0.z; r2 = p;  p = z0.w*z0.w; r3 = p;
          p = z1.x*z1.x; r4 = p;  p = z1.y*z1.y; r5 = p;
          p = z1.z*z1.z; r6 = p;  p = z1.w*z1.w; r7 = p; }
        SQ8(z2,  z3)  SQ8(z4,  z5)  SQ8(z6,  z7)
        SQ8(z8,  z9)  SQ8(z10, z11) SQ8(z12, z13) SQ8(z14, z15)
        A = ((r0 + r1) + (r2 + r3)) + ((r4 + r5) + (r6 + r7));
    }

    const int k0 = q * KCHUNK;
    float best = 3.4e38f;
    int bk = k0;
#pragma unroll 1
    for (int kk = 0; kk < KCHUNK; ++kk) {
        const int k = k0 + kk;
        const float4* ep = (const float4*)(e + (size_t)k * DIM);
        float m = 0.0f;
        DOT4(0,  z0)  DOT4(1,  z1)  DOT4(2,  z2)  DOT4(3,  z3)
        DOT4(4,  z4)  DOT4(5,  z5)  DOT4(6,  z6)  DOT4(7,  z7)
        DOT4(8,  z8)  DOT4(9,  z9)  DOT4(10, z10) DOT4(11, z11)
        DOT4(12, z12) DOT4(13, z13) DOT4(14, z14) DOT4(15, z15)
        float s;
        {
#pragma clang fp contract(off)
            float twoM = 2.0f * m;
            float t = A - twoM;
            s = t + En[k];
        }
        if (s < best) { best = s; bk = k; }
    }

    __shared__ float ls[KSPLIT][64];
    __shared__ int   li[KSPLIT][64];
    ls[q][lane] = best;
    li[q][lane] = bk;
    __syncthreads();

    if (threadIdx.x < 64) {
        float b0 = ls[0][lane];
        int   kb = li[0][lane];
#pragma unroll
        for (int qq = 1; qq < KSPLIT; ++qq) {
            float sq = ls[qq][lane];
            if (sq < b0) { b0 = sq; kb = li[qq][lane]; }
        }
        const int b  = n >> 10;
        const int hw = n & 1023;
        const float4* erp = (const float4*)(e + (size_t)kb * DIM);
        float* o0 = out + (size_t)b * 65536 + hw;
        float lsum = 0.0f;
        EPI4(0,  z0)  EPI4(1,  z1)  EPI4(2,  z2)  EPI4(3,  z3)
        EPI4(4,  z4)  EPI4(5,  z5)  EPI4(6,  z6)  EPI4(7,  z7)
        EPI4(8,  z8)  EPI4(9,  z9)  EPI4(10, z10) EPI4(11, z11)
        EPI4(12, z12) EPI4(13, z13) EPI4(14, z14) EPI4(15, z15)
        out[OUT1_OFF + n] = (float)kb;
#pragma unroll
        for (int off = 32; off > 0; off >>= 1)
            lsum += __shfl_down(lsum, off, 64);
        if (lane == 0)
            atomicAdd(&out[LOSS_OFF], lsum * (1.25f / 4194304.0f));
    }
}

// ======================= MFMA path =======================
// exact fp32 rescore, bit-identical to the validated old-kernel inner loop
__device__ __forceinline__ float vq_rescore(const int k,
        const float* __restrict__ e, const float* __restrict__ En, const float A,
        const float4 z0, const float4 z1, const float4 z2, const float4 z3,
        const float4 z4, const float4 z5, const float4 z6, const float4 z7,
        const float4 z8, const float4 z9, const float4 z10, const float4 z11,
        const float4 z12, const float4 z13, const float4 z14, const float4 z15) {
    const float4* ep = (const float4*)(e + (size_t)k * DIM);
    float m = 0.0f;
    DOT4(0,  z0)  DOT4(1,  z1)  DOT4(2,  z2)  DOT4(3,  z3)
    DOT4(4,  z4)  DOT4(5,  z5)  DOT4(6,  z6)  DOT4(7,  z7)
    DOT4(8,  z8)  DOT4(9,  z9)  DOT4(10, z10) DOT4(11, z11)
    DOT4(12, z12) DOT4(13, z13) DOT4(14, z14) DOT4(15, z15)
    float s;
    {
#pragma clang fp contract(off)
        const float twoM = 2.0f * m;
        const float t = A - twoM;
        s = t + En[k];
    }
    return s;
}

// prep2: En (exact, unchanged math) + eB = -2*bf16(e) packed in B-frag order
//   eB layout: [group G=0..63][frag f=0..1][lane l=0..63][8 bf16]
//   lane l of (G,f) holds e[G*16 + (l&15)][f*32 + (l>>4)*8 + 0..7]
// + MFMA fragment-layout self-test (asymmetric); flag!=0 -> main kernel takes
//   the exact full-scan path for every row (slow but correct).
__global__ __launch_bounds__(256) void vq_prep2(const float* __restrict__ e,
                                                float* __restrict__ En,
                                                unsigned short* __restrict__ eB,
                                                int* __restrict__ flg,
                                                float* __restrict__ out) {
    const int tid = blockIdx.x * 256 + threadIdx.x;   // 0..8191
    if (tid == 0) out[LOSS_OFF] = 0.0f;
    {
        const int G = tid >> 7, rem = tid & 127, f = rem >> 6, l = rem & 63;
        const int code = G * 16 + (l & 15);
        const int d0 = f * 32 + ((l >> 4) << 3);
        const float4* sp = (const float4*)(e + (size_t)code * DIM + d0);
        float4 a = sp[0], b = sp[1];
        a.x *= -2.f; a.y *= -2.f; a.z *= -2.f; a.w *= -2.f;
        b.x *= -2.f; b.y *= -2.f; b.z *= -2.f; b.w *= -2.f;
        s16x8 v = pack_bf8(a, b);
        *(s16x8*)(eB + (size_t)tid * 8) = v;
    }
    if (tid < NUM_E) {
        float xr[DIM];
        const float4* ep = (const float4*)(e + (size_t)tid * DIM);
#pragma unroll
        for (int i = 0; i < 16; ++i) {
            float4 v = ep[i];
            xr[4*i+0] = v.x; xr[4*i+1] = v.y; xr[4*i+2] = v.z; xr[4*i+3] = v.w;
        }
        En[tid] = np_sumsq64_arr(xr);
    }
    // ---- MFMA layout self-test (block 0, wave 0) ----
    if (blockIdx.x == 0 && threadIdx.x < 64) {
        const int l = threadIdx.x, cc = l & 15, hh = l >> 4;
        s16x8 ta, tb;
#pragma unroll
        for (int j = 0; j < 8; ++j) {
            const int k = hh * 8 + j;
            ta[j] = (short)((cc == 0) ? f2bf((float)(k + 1)) : 0);
            tb[j] = (short)((cc == 0) ? f2bf((float)(2 * k + 1))
                          : (cc == 3 && k == 2) ? f2bf(1.0f) : 0);
        }
        f32x4_t td = {0.f, 0.f, 0.f, 0.f};
        td = __builtin_amdgcn_mfma_f32_16x16x32_bf16(ta, tb, td, 0, 0, 0);
        int ok = 1;
#pragma unroll
        for (int j = 0; j < 4; ++j) {
            const int row = hh * 4 + j;
            const float expv = (cc == 0) ? (row == 0 ? 22352.0f : 0.0f)
                             : (cc == 3) ? (row == 0 ? 3.0f : 0.0f) : 0.0f;
            ok = ok && (td[j] == expv);
        }
        const unsigned long long bal = __ballot(ok);
        if (l == 0) flg[0] = (bal == 0xFFFFFFFFFFFFFFFFULL) ? 0 : 1;
    }
}

// main: 512 thr = 8 waves x 32 rows = 256 rows/block; grid 256 (1 block/CU).
// R3 post-mortem: 80us with MfmaUtil 8%/VALU 14%/HBM 4% = latency-bound on
// L2-resident eB (each wave streamed 256 KB from L2, 512 MB chip-wide,
// ~300-500cy per load feeding the MFMA chain). Fix: eB (128 KB) fits LDS —
// stage ONCE per block via global_load_lds (one barrier total; barrier
// semantics drain vmcnt => staging complete), then both phases read LDS
// (~64cy, 614 GB/s/CU vs 135 GB/s/CU L2 share). Waves own their rows:
// no barrier between phase1/phase2, none before the epilogue.
__global__ __launch_bounds__(512, 2)
void vq_mfma_kernel(const float* __restrict__ z,
                    const float* __restrict__ e,
                    const float* __restrict__ En,
                    const unsigned short* __restrict__ eB,
                    const int* __restrict__ flg,
                    float* __restrict__ out) {
    __shared__ unsigned short lds_e[65536];           // 128 KB, frag order
    __shared__ unsigned short candk[256][CAND_CAP];   // 11.5 KB (u16 codes)
    __shared__ int candcnt[256];                      // 1 KB

    const int tid  = threadIdx.x;
    const int lane = tid & 63;
    const int w    = __builtin_amdgcn_readfirstlane(tid >> 6);  // 0..7
    const int cc   = lane & 15;   // B-col (code within group) / A-row
    const int hh   = lane >> 4;   // k-subgroup / D-row-group
    const int n0   = blockIdx.x * 256;
    const int bad  = flg[0];

    // ---- stage eB slice w (16 KB) into LDS: 16 x 1KB global_load_lds ----
#pragma unroll
    for (int i = 0; i < 16; ++i) {
        const int seg = w * 16 + i;                   // 1 KB segments, linear
        __builtin_amdgcn_global_load_lds(
            AS1C(eB + (size_t)seg * 512 + (size_t)lane * 8),
            AS3P(lds_e + seg * 512), 16, 0, 0);
    }

    if (lane < 32) candcnt[w * 32 + lane] = 0;

    // z fragments (bf16): rows w*32+cc (set A) and +16 (set B), K halves 0/1
    s16x8 az0, az1, az2, az3;
    {
        const float* zr0 = z + (size_t)(n0 + w * 32 + cc) * DIM + hh * 8;
        const float* zr1 = zr0 + (size_t)16 * DIM;
        az0 = pack_bf8(*(const float4*)(zr0),      *(const float4*)(zr0 + 4));
        az1 = pack_bf8(*(const float4*)(zr0 + 32), *(const float4*)(zr0 + 36));
        az2 = pack_bf8(*(const float4*)(zr1),      *(const float4*)(zr1 + 4));
        az3 = pack_bf8(*(const float4*)(zr1 + 32), *(const float4*)(zr1 + 36));
    }

    __syncthreads();   // staging + candcnt init complete (vmcnt drained here)

    if (!bad) {
        const s16x8* lp = (const s16x8*)lds_e;        // [u*128 + f*64 + lane]

        // ---------------- phase 1: min scan (LDS, no barriers) ------------
        float b1v[8];
#pragma unroll
        for (int j = 0; j < 8; ++j) b1v[j] = 3.4e38f;

#pragma unroll 8
        for (int u = 0; u < 64; ++u) {
            const s16x8 eb0 = lp[u * 128 + lane];
            const s16x8 eb1 = lp[u * 128 + 64 + lane];
            f32x4_t accA = {0.f, 0.f, 0.f, 0.f};
            f32x4_t accB = {0.f, 0.f, 0.f, 0.f};
            accA = __builtin_amdgcn_mfma_f32_16x16x32_bf16(az0, eb0, accA, 0, 0, 0);
            accA = __builtin_amdgcn_mfma_f32_16x16x32_bf16(az1, eb1, accA, 0, 0, 0);
            accB = __builtin_amdgcn_mfma_f32_16x16x32_bf16(az2, eb0, accB, 0, 0, 0);
            accB = __builtin_amdgcn_mfma_f32_16x16x32_bf16(az3, eb1, accB, 0, 0, 0);
#pragma unroll
            for (int j = 0; j < 4; ++j) {
                b1v[j]     = fminf(b1v[j],     accA[j]);
                b1v[j + 4] = fminf(b1v[j + 4], accB[j]);
            }
        }

        // per-row bf16 min across the 16 cc-classes -> threshold
        float th[8];
#pragma unroll
        for (int j = 0; j < 8; ++j) {
            float mv = b1v[j];
            mv = fminf(mv, __shfl_xor(mv, 1));
            mv = fminf(mv, __shfl_xor(mv, 2));
            mv = fminf(mv, __shfl_xor(mv, 4));
            mv = fminf(mv, __shfl_xor(mv, 8));
            th[j] = mv + MARGIN;
        }

        // ---------------- phase 2: candidate collection (LDS) -------------
#pragma unroll 4
        for (int u = 0; u < 64; ++u) {
            const s16x8 eb0 = lp[u * 128 + lane];
            const s16x8 eb1 = lp[u * 128 + 64 + lane];
            f32x4_t accA = {0.f, 0.f, 0.f, 0.f};
            f32x4_t accB = {0.f, 0.f, 0.f, 0.f};
            accA = __builtin_amdgcn_mfma_f32_16x16x32_bf16(az0, eb0, accA, 0, 0, 0);
            accA = __builtin_amdgcn_mfma_f32_16x16x32_bf16(az1, eb1, accA, 0, 0, 0);
            accB = __builtin_amdgcn_mfma_f32_16x16x32_bf16(az2, eb0, accB, 0, 0, 0);
            accB = __builtin_amdgcn_mfma_f32_16x16x32_bf16(az3, eb1, accB, 0, 0, 0);
            float worst = accA[0] - th[0];
            worst = fminf(worst, accA[1] - th[1]);
            worst = fminf(worst, accA[2] - th[2]);
            worst = fminf(worst, accA[3] - th[3]);
            worst = fminf(worst, accB[0] - th[4]);
            worst = fminf(worst, accB[1] - th[5]);
            worst = fminf(worst, accB[2] - th[6]);
            worst = fminf(worst, accB[3] - th[7]);
            if (__any(worst <= 0.0f)) {
                const int kc = u * 16 + cc;
#pragma unroll
                for (int j = 0; j < 4; ++j) {
                    if (accA[j] <= th[j]) {
                        const int rr = w * 32 + hh * 4 + j;
                        const int slot = atomicAdd(&candcnt[rr], 1);
                        if (slot < CAND_CAP) candk[rr][slot] = (unsigned short)kc;
                    }
                    if (accB[j] <= th[j + 4]) {
                        const int rr = w * 32 + 16 + hh * 4 + j;
                        const int slot = atomicAdd(&candcnt[rr], 1);
                        if (slot < CAND_CAP) candk[rr][slot] = (unsigned short)kc;
                    }
                }
            }
        }
    }

    // -------- epilogue: exact rescore + outputs (wave w, its 32 rows) -----
    if (lane < 32) {
        const int r = w * 32 + lane;
        const int n = n0 + r;
        float4 z0,z1,z2,z3,z4,z5,z6,z7,z8,z9,z10,z11,z12,z13,z14,z15;
        {
            const float4* zp = (const float4*)(z + (size_t)n * DIM);
            z0=zp[0]; z1=zp[1]; z2=zp[2]; z3=zp[3]; z4=zp[4]; z5=zp[5]; z6=zp[6]; z7=zp[7];
            z8=zp[8]; z9=zp[9]; z10=zp[10]; z11=zp[11]; z12=zp[12]; z13=zp[13]; z14=zp[14]; z15=zp[15];
        }
        float A;
        {
#pragma clang fp contract(off)
            float r0,r1,r2,r3,r4,r5,r6,r7;
            { float p;
              p = z0.x*z0.x; r0 = p;  p = z0.y*z0.y; r1 = p;
              p = z0.z*z0.z; r2 = p;  p = z0.w*z0.w; r3 = p;
              p = z1.x*z1.x; r4 = p;  p = z1.y*z1.y; r5 = p;
              p = z1.z*z1.z; r6 = p;  p = z1.w*z1.w; r7 = p; }
            SQ8(z2,  z3)  SQ8(z4,  z5)  SQ8(z6,  z7)
            SQ8(z8,  z9)  SQ8(z10, z11) SQ8(z12, z13) SQ8(z14, z15)
            A = ((r0 + r1) + (r2 + r3)) + ((r4 + r5) + (r6 + r7));
        }
#define RS(K) vq_rescore((K), e, En, A, z0,z1,z2,z3,z4,z5,z6,z7,z8,z9,z10,z11,z12,z13,z14,z15)
        const int cnt = bad ? 0 : candcnt[r];
        float best = 3.4e38f;
        int bk = 0x7FFFFFFF;
        if (cnt >= 1 && cnt <= CAND_CAP) {
            for (int i = 0; i < cnt; ++i) {
                const int k = candk[r][i];
                const float s = RS(k);
                if (s < best || (s == best && k < bk)) { best = s; bk = k; }
            }
        }
        if ((unsigned)bk > 1023u) {   // bad-layout flag / overflow: exact full scan
            best = 3.4e38f; bk = 0;
            for (int k = 0; k < NUM_E; ++k) {
                const float s = RS(k);
                if (s < best) { best = s; bk = k; }
            }
        }
#undef RS
        const int b  = n >> 10;
        const int hw = n & 1023;
        const float4* erp = (const float4*)(e + (size_t)bk * DIM);
        float* o0 = out + (size_t)b * 65536 + hw;
        float lsum = 0.0f;
        EPI4(0,  z0)  EPI4(1,  z1)  EPI4(2,  z2)  EPI4(3,  z3)
        EPI4(4,  z4)  EPI4(5,  z5)  EPI4(6,  z6)  EPI4(7,  z7)
        EPI4(8,  z8)  EPI4(9,  z9)  EPI4(10, z10) EPI4(11, z11)
        EPI4(12, z12) EPI4(13, z13) EPI4(14, z14) EPI4(15, z15)
        out[OUT1_OFF + n] = (float)bk;
#pragma unroll
        for (int off = 16; off > 0; off >>= 1)
            lsum += __shfl_down(lsum, off, 32);
        if (lane == 0)
            atomicAdd(&out[LOSS_OFF], lsum * (1.25f / 4194304.0f));
    }
}

extern "C" void kernel_launch(void* const* d_in, const int* in_sizes, int n_in,
                              void* d_out, int out_size, void* d_ws, size_t ws_size,
                              hipStream_t stream) {
    const float* z = (const float*)d_in[0];       // [65536, 64] fp32
    const float* e = (const float*)d_in[1];       // [1024, 64] fp32
    float* out = (float*)d_out;
    float* En  = (float*)d_ws;                    // 1024 fp32 norms (4 KB)

    if (ws_size >= WS_NEED) {
        unsigned short* eB = (unsigned short*)((char*)d_ws + WS_EB_OFF);
        int* flg = (int*)((char*)d_ws + WS_FLAG_OFF);
        vq_prep2<<<32, 256, 0, stream>>>(e, En, eB, flg, out);
        vq_mfma_kernel<<<NROWS / 256, 512, 0, stream>>>(z, e, En, eB, flg, out);
    } else {
        vq_prep_kernel<<<NUM_E / 256, 256, 0, stream>>>(e, En, out);
        vq_fused_kernel<<<NROWS / 64, 256, 0, stream>>>(z, e, En, out);
    }
}